// Round 18
// baseline (326.964 us; speedup 1.0000x reference)
//
#include <hip/hip_runtime.h>
#include <cstdint>
#include <cstddef>

#define NPTS 4096
#define NBATCH 8
#define CIN 128
#define KNB 32
#define EPSC 1e-5f

// ---------------------------------------------------------------------------
// Kernel A: ball query, wave per 4 points, joint scan (r16). Pure-f32 band.
// ---------------------------------------------------------------------------
__global__ __launch_bounds__(1024) void ball_query_kernel(
    const float* __restrict__ pos, int* __restrict__ idx_inc,
    int* __restrict__ idx_exc, int* __restrict__ flags,
    float* __restrict__ pos_out)
{
    __shared__ float sx[NPTS], sy[NPTS], sz[NPTS];   // 48 KB
    const int tid  = threadIdx.x;
    const int lane = tid & 63;
    const int wv   = tid >> 6;                       // 0..15
    const int pbase = blockIdx.x * 64;               // 64 points per block
    const int b = pbase >> 12;
    const float* pb = pos + (size_t)b * NPTS * 3;

    const float T_HI = (float)(0.0225 + 3e-7);
    const float T_LO = (float)(0.0225 - 3e-7);

    for (int j = tid; j < NPTS; j += 1024) {
        sx[j] = pb[j*3+0]; sy[j] = pb[j*3+1]; sz[j] = pb[j*3+2];
    }
    if ((pbase & (NPTS - 1)) == 0) {                 // pos passthrough
        const float4* src = (const float4*)pb;
        float4* dst = (float4*)(pos_out + (size_t)b * NPTS * 3);
        for (int i = tid; i < NPTS * 3 / 4; i += 1024) dst[i] = src[i];
    }
    __syncthreads();

    const int p0 = pbase + wv * 4;                   // this wave's 4 points
    float px[4], py[4], pz[4];
    int cnt[4]   = {0, 0, 0, 0};
    int first[4] = {0, 0, 0, 0};
    unsigned long long dif[4] = {0ull, 0ull, 0ull, 0ull};
    int* op[4];
#pragma unroll
    for (int q = 0; q < 4; ++q) {
        const int ml = (p0 + q) & (NPTS - 1);
        px[q] = sx[ml]; py[q] = sy[ml]; pz[q] = sz[ml];
        op[q] = idx_inc + (size_t)(p0 + q) * KNB;
    }

    for (int it = 0; it < NPTS / 64; ++it) {
        const int j = it * 64 + lane;
        const float cx = sx[j], cy = sy[j], cz = sz[j];
        int ndone = 0;
#pragma unroll
        for (int q = 0; q < 4; ++q) {
            if (cnt[q] < KNB) {                      // wave-uniform branch
                const float dx = px[q] - cx, dy = py[q] - cy, dz = pz[q] - cz;
                const float d2 = fmaf(dx, dx, fmaf(dy, dy, dz * dz));
                const unsigned long long mi = __ballot(d2 < T_HI);
                const unsigned long long me = __ballot(d2 < T_LO);
                dif[q] |= (mi ^ me);
                if (cnt[q] == 0 && mi) first[q] = it * 64 + __ffsll(mi) - 1;
                if (d2 < T_HI) {
                    const int r = cnt[q] + (int)__builtin_amdgcn_mbcnt_hi(
                        (unsigned)(mi >> 32),
                        __builtin_amdgcn_mbcnt_lo((unsigned)mi, 0u));
                    if (r < KNB) op[q][r] = j;
                }
                cnt[q] += __popcll(mi);
            } else {
                ndone++;
            }
        }
        if (ndone == 4) break;
    }

#pragma unroll
    for (int q = 0; q < 4; ++q) {
        const int si = cnt[q] < KNB ? cnt[q] : KNB;
        if (lane >= si && lane < KNB) op[q][lane] = first[q];   // pad w/ first hit
        const int flg = (dif[q] != 0ull) ? 1 : 0;
        if (flg) {                                   // rare, wave-uniform
            int cnt_e = 0, first_e = 0;
            int* oe = idx_exc + (size_t)(p0 + q) * KNB;
            const float qx = px[q], qy = py[q], qz = pz[q];
            for (int it = 0; it < NPTS / 64; ++it) {
                const int j = it * 64 + lane;
                const float dx = qx - sx[j], dy = qy - sy[j], dz = qz - sz[j];
                const float d2 = fmaf(dx, dx, fmaf(dy, dy, dz * dz));
                const unsigned long long me = __ballot(d2 < T_LO);
                if (cnt_e == 0 && me) first_e = it * 64 + __ffsll(me) - 1;
                if (d2 < T_LO) {
                    const int r = cnt_e + (int)__builtin_amdgcn_mbcnt_hi(
                        (unsigned)(me >> 32),
                        __builtin_amdgcn_mbcnt_lo((unsigned)me, 0u));
                    if (r < KNB) oe[r] = j;
                }
                cnt_e += __popcll(me);
                if (cnt_e >= KNB) break;
            }
            const int se = cnt_e < KNB ? cnt_e : KNB;
            if (lane >= se && lane < KNB) oe[lane] = first_e;
        }
        if (lane == 0) flags[p0 + q] = flg;
    }
}

// ---------------------------------------------------------------------------
// Tiled f32 GEMM  C[r, col] = epilogue( sum_k A[r,k] * W[col, woff+k] )
// BM x 128 tile, BK=32. LDS pads +1 (stride%32==1 -> worst 2-way alias, free).
// Register double-buffer: chunk kc+1's global loads are issued before the
// barrier and consumed at the next iteration's LDS-write, so HBM latency
// hides under chunk kc's compute. FMA order (kc,kk ascending) unchanged.
// ---------------------------------------------------------------------------
template<int BM, int KTOT, int EPI>
__global__ __launch_bounds__(256) void gemm_bn_kernel(
    const float* __restrict__ A, const float* __restrict__ W,
    int wstride, int woff,
    const float* __restrict__ gg, const float* __restrict__ bb,
    const float* __restrict__ mm, const float* __restrict__ vv,
    const float* __restrict__ X,
    float* __restrict__ C, int cstride)
{
    constexpr int MR = BM / 16;                  // rows per thread (8 or 4)
    constexpr int NK = KTOT / 32;
    __shared__ float At[32][BM + 1];
    __shared__ float Wt[32][129];
    const int tid  = threadIdx.x;
    const int lane = tid & 63;
    const int wv   = tid >> 6;
    const int tr = ((wv >> 1) << 3) | (lane >> 3);   // 0..15
    const int tc = ((wv & 1) << 3) | (lane & 7);     // 0..15
    const int rowbase = blockIdx.x * BM;
    const int colbase = blockIdx.y * 128;
    const int k4   = (tid & 7) * 4;                  // K offset within chunk
    const int lrow = tid >> 3;                       // 0..31

    float acc[MR][8];
#pragma unroll
    for (int i = 0; i < MR; ++i)
#pragma unroll
        for (int j = 0; j < 8; ++j) acc[i][j] = 0.f;

    float4 pa[BM / 32];
    float pw[4][4];
    // prologue: load chunk 0 into registers
#pragma unroll
    for (int p = 0; p < BM / 32; ++p) {
        const int r = lrow + p * 32;
        pa[p] = *(const float4*)&A[(size_t)(rowbase + r) * KTOT + k4];
    }
#pragma unroll
    for (int p = 0; p < 4; ++p) {
        const int c = lrow + p * 32;
        const float* wp = &W[(size_t)(colbase + c) * wstride + woff + k4];
        pw[p][0] = wp[0]; pw[p][1] = wp[1]; pw[p][2] = wp[2]; pw[p][3] = wp[3];
    }

    for (int kc = 0; kc < NK; ++kc) {
        // commit staged registers to LDS
#pragma unroll
        for (int p = 0; p < BM / 32; ++p) {
            const int r = lrow + p * 32;
            At[k4+0][r] = pa[p].x; At[k4+1][r] = pa[p].y;
            At[k4+2][r] = pa[p].z; At[k4+3][r] = pa[p].w;
        }
#pragma unroll
        for (int p = 0; p < 4; ++p) {
            const int c = lrow + p * 32;
            Wt[k4+0][c] = pw[p][0]; Wt[k4+1][c] = pw[p][1];
            Wt[k4+2][c] = pw[p][2]; Wt[k4+3][c] = pw[p][3];
        }
        // prefetch chunk kc+1 (latency hides under this chunk's compute)
        if (kc + 1 < NK) {
            const int ko = (kc + 1) * 32 + k4;
#pragma unroll
            for (int p = 0; p < BM / 32; ++p) {
                const int r = lrow + p * 32;
                pa[p] = *(const float4*)&A[(size_t)(rowbase + r) * KTOT + ko];
            }
#pragma unroll
            for (int p = 0; p < 4; ++p) {
                const int c = lrow + p * 32;
                const float* wp = &W[(size_t)(colbase + c) * wstride + woff + ko];
                pw[p][0] = wp[0]; pw[p][1] = wp[1]; pw[p][2] = wp[2]; pw[p][3] = wp[3];
            }
        }
        __syncthreads();
#pragma unroll 4
        for (int kk = 0; kk < 32; ++kk) {
            float a[MR], w[8];
            if constexpr (MR == 8) {
                *(float4*)&a[0] = *(const float4*)&At[kk][tr*8];
                *(float4*)&a[4] = *(const float4*)&At[kk][tr*8+4];
            } else {
                *(float4*)&a[0] = *(const float4*)&At[kk][tr*4];
            }
            *(float4*)&w[0] = *(const float4*)&Wt[kk][tc*8];
            *(float4*)&w[4] = *(const float4*)&Wt[kk][tc*8+4];
#pragma unroll
            for (int i = 0; i < MR; ++i)
#pragma unroll
                for (int j = 0; j < 8; ++j)
                    acc[i][j] = fmaf(a[i], w[j], acc[i][j]);
        }
        __syncthreads();
    }

    float s[8], t[8];
#pragma unroll
    for (int j = 0; j < 8; ++j) {
        const int col = colbase + tc * 8 + j;
        const float sc = gg[col] / sqrtf(vv[col] + EPSC);
        s[j] = sc;
        t[j] = (EPI == 0) ? 0.f : (bb[col] - mm[col] * sc);
    }
#pragma unroll
    for (int i = 0; i < MR; ++i) {
        const int r = rowbase + tr * MR + i;
        float o[8];
#pragma unroll
        for (int j = 0; j < 8; ++j) {
            float vl = acc[i][j] * s[j];
            if (EPI != 0) vl += t[j];
            if (EPI == 2) vl += X[(size_t)r * 128 + colbase + tc * 8 + j];
            if (EPI >= 1) vl = fmaxf(vl, 0.f);
            o[j] = vl;
        }
        float* cp = &C[(size_t)r * cstride + colbase + tc * 8];
        *(float4*)&cp[0] = *(const float4*)&o[0];
        *(float4*)&cp[4] = *(const float4*)&o[4];
    }
}

// ---------------------------------------------------------------------------
// Kernel C: gather + rel contribution + max-pool, LDS-table edition (r14).
// ---------------------------------------------------------------------------
__global__ __launch_bounds__(256) void group_max_kernel(
    const float* __restrict__ pos, const int* __restrict__ idx_inc,
    const int* __restrict__ idx_exc, const int* __restrict__ flags,
    const float* __restrict__ xws,
    const float* __restrict__ W1, const float* __restrict__ g1,
    const float* __restrict__ b1, const float* __restrict__ m1,
    const float* __restrict__ v1,
    float* __restrict__ f_inc, float* __restrict__ f_exc)
{
    __shared__ float4 relbuf[2][4][KNB];             // 4 KB
    const int tid  = threadIdx.x;
    const int lane = tid & 63;
    const int wv   = tid >> 6;
    const int p = blockIdx.x * 4 + wv;
    const int b = p >> 12;
    const int mloc = p & (NPTS - 1);
    const float* pb = pos + (size_t)b * NPTS * 3;
    const char* xws_b = (const char*)(xws + (size_t)b * NPTS * 128);
    const int o0 = lane * 2;
    const int lane8 = lane * 8;

    const float w00 = W1[(size_t)o0*131+0], w01 = W1[(size_t)o0*131+1], w02 = W1[(size_t)o0*131+2];
    const float w10 = W1[(size_t)(o0+1)*131+0], w11 = W1[(size_t)(o0+1)*131+1], w12 = W1[(size_t)(o0+1)*131+2];
    const float s0 = g1[o0]   / sqrtf(v1[o0]   + EPSC);
    const float s1 = g1[o0+1] / sqrtf(v1[o0+1] + EPSC);
    const float t0 = b1[o0]   - m1[o0]   * s0;
    const float t1 = b1[o0+1] - m1[o0+1] * s1;
    const float q00 = w00*s0, q01 = w01*s0, q02 = w02*s0;
    const float q10 = w10*s1, q11 = w11*s1, q12 = w12*s1;

    const float pmx = pb[mloc*3+0], pmy = pb[mloc*3+1], pmz = pb[mloc*3+2];
    const int flg = flags[p];

    {   // preload inc table
        const int j = idx_inc[(size_t)p * KNB + (lane & 31)];
        const float* pj = &pb[j*3];
        const float rx = (pj[0] - pmx) / 0.15f;
        const float ry = (pj[1] - pmy) / 0.15f;
        const float rz = (pj[2] - pmz) / 0.15f;
        if (lane < KNB)
            relbuf[0][wv][lane] = make_float4(rx, ry, rz, __int_as_float(j << 9));
    }
    if (flg) {  // preload exc table (rare; no barrier inside)
        const int j = idx_exc[(size_t)p * KNB + (lane & 31)];
        const float* pj = &pb[j*3];
        const float rx = (pj[0] - pmx) / 0.15f;
        const float ry = (pj[1] - pmy) / 0.15f;
        const float rz = (pj[2] - pmz) / 0.15f;
        if (lane < KNB)
            relbuf[1][wv][lane] = make_float4(rx, ry, rz, __int_as_float(j << 9));
    }
    __syncthreads();

    {
        const float4* rt = relbuf[0][wv];
        float acc0 = 0.f, acc1 = 0.f;
#pragma unroll 8
        for (int k = 0; k < KNB; ++k) {
            const float4 rv = rt[k];
            const int ofs = __float_as_int(rv.w);
            const float2 xw = *(const float2*)(xws_b + ofs + lane8);
            const float v0 = fmaf(rv.x, q00, fmaf(rv.y, q01, fmaf(rv.z, q02, t0 + xw.x)));
            const float v1v = fmaf(rv.x, q10, fmaf(rv.y, q11, fmaf(rv.z, q12, t1 + xw.y)));
            acc0 = fmaxf(acc0, v0);
            acc1 = fmaxf(acc1, v1v);
        }
        float2 r2v; r2v.x = acc0; r2v.y = acc1;
        *(float2*)&f_inc[(size_t)p * 128 + o0] = r2v;
    }
    if (flg) {
        const float4* rt = relbuf[1][wv];
        float e0 = 0.f, e1 = 0.f;
#pragma unroll 8
        for (int k = 0; k < KNB; ++k) {
            const float4 rv = rt[k];
            const int ofs = __float_as_int(rv.w);
            const float2 xw = *(const float2*)(xws_b + ofs + lane8);
            const float v0 = fmaf(rv.x, q00, fmaf(rv.y, q01, fmaf(rv.z, q02, t0 + xw.x)));
            const float v1v = fmaf(rv.x, q10, fmaf(rv.y, q11, fmaf(rv.z, q12, t1 + xw.y)));
            e0 = fmaxf(e0, v0);
            e1 = fmaxf(e1, v1v);
        }
        float2 ev; ev.x = e0; ev.y = e1;
        *(float2*)&f_exc[(size_t)p * 128 + o0] = ev;
    }
}

// ---------------------------------------------------------------------------
// Kernel E: per-flagged-point MLP on f_exc; blend OUTPUT-space midpoint.
// ---------------------------------------------------------------------------
__global__ __launch_bounds__(256) void fixup_kernel(
    const int* __restrict__ flags, const float* __restrict__ f_exc,
    const float* __restrict__ x,
    const float* __restrict__ W2, const float* __restrict__ g2,
    const float* __restrict__ b2, const float* __restrict__ m2,
    const float* __restrict__ v2,
    const float* __restrict__ W3, const float* __restrict__ g3,
    const float* __restrict__ b3, const float* __restrict__ m3,
    const float* __restrict__ v3,
    float* __restrict__ y_out)
{
    const int lane = threadIdx.x & 63;
    const int wv   = threadIdx.x >> 6;
    const int p = blockIdx.x * 4 + wv;
    if (flags[p] == 0) return;

    const float2 fv = *(const float2*)&f_exc[(size_t)p * 128 + 2 * lane];

    float acc[8];
#pragma unroll
    for (int u = 0; u < 8; ++u) acc[u] = 0.f;
    for (int cc = 0; cc < 64; ++cc) {
        float fx = __shfl(fv.x, cc);
        float fy = __shfl(fv.y, cc);
#pragma unroll
        for (int u = 0; u < 8; ++u) {
            const float* wr = &W2[(size_t)(64 * u + lane) * 128 + 2 * cc];
            acc[u] += fx * wr[0] + fy * wr[1];
        }
    }
    float hreg[8];
#pragma unroll
    for (int u = 0; u < 8; ++u) {
        int o = 64 * u + lane;
        float s = g2[o] / sqrtf(v2[o] + EPSC);
        float t = b2[o] - m2[o] * s;
        hreg[u] = fmaxf(acc[u] * s + t, 0.f);
    }

    const int o0 = 2 * lane, o1 = 2 * lane + 1;
    float a0 = 0.f, a1 = 0.f;
#pragma unroll
    for (int u = 0; u < 8; ++u) {
        float hu = hreg[u];
        for (int cc = 0; cc < 64; ++cc) {
            float hc = __shfl(hu, cc);
            int c = 64 * u + cc;
            a0 += hc * W3[(size_t)o0 * 512 + c];
            a1 += hc * W3[(size_t)o1 * 512 + c];
        }
    }
    float s0 = g3[o0] / sqrtf(v3[o0] + EPSC), t0 = b3[o0] - m3[o0] * s0;
    float s1 = g3[o1] / sqrtf(v3[o1] + EPSC), t1 = b3[o1] - m3[o1] * s1;
    float e0 = fmaxf(a0 * s0 + t0 + x[(size_t)p * 128 + o0], 0.f);
    float e1 = fmaxf(a1 * s1 + t1 + x[(size_t)p * 128 + o1], 0.f);

    float2 cur = *(float2*)&y_out[(size_t)p * 128 + o0];
    float2 nv; nv.x = 0.5f * (cur.x + e0); nv.y = 0.5f * (cur.y + e1);
    *(float2*)&y_out[(size_t)p * 128 + o0] = nv;
}

// ---------------------------------------------------------------------------
extern "C" void kernel_launch(void* const* d_in, const int* in_sizes, int n_in,
                              void* d_out, int out_size, void* d_ws, size_t ws_size,
                              hipStream_t stream)
{
    const float* pos = (const float*)d_in[0];
    const float* x   = (const float*)d_in[1];
    const float* W1  = (const float*)d_in[2];
    const float* g1  = (const float*)d_in[3];
    const float* b1  = (const float*)d_in[4];
    const float* m1  = (const float*)d_in[5];
    const float* v1  = (const float*)d_in[6];
    const float* W2  = (const float*)d_in[7];
    const float* g2  = (const float*)d_in[8];
    const float* b2  = (const float*)d_in[9];
    const float* m2  = (const float*)d_in[10];
    const float* v2  = (const float*)d_in[11];
    const float* W3  = (const float*)d_in[12];
    const float* g3  = (const float*)d_in[13];
    const float* b3  = (const float*)d_in[14];
    const float* m3  = (const float*)d_in[15];
    const float* v3  = (const float*)d_in[16];

    float* out = (float*)d_out;
    float* pos_out = out;                     // 8*4096*3 floats
    float* y_out   = out + 98304;             // 8*4096*128 floats

    char* ws = (char*)d_ws;
    int*   idx_inc = (int*)ws;                              // 4 MB @ 0
    int*   idx_exc = (int*)(ws + ((size_t)4  << 20));       // 4 MB @ 4M
    int*   flags   = (int*)(ws + ((size_t)8  << 20));       // 128 KB @ 8M
    float* xws     = (float*)(ws + ((size_t)9  << 20));     // 16 MB @ 9M
    float* f_inc   = (float*)(ws + ((size_t)25 << 20));     // 16 MB @ 25M
    float* f_exc   = (float*)(ws + ((size_t)41 << 20));     // 16 MB @ 41M
    float* h1      = (float*)(ws + ((size_t)57 << 20));     // 64 MB @ 57M
    (void)ws_size; (void)in_sizes; (void)n_in; (void)out_size;

    // A: ball query (joint 4-point scan) + pos passthrough
    ball_query_kernel<<<512, 1024, 0, stream>>>(pos, idx_inc, idx_exc, flags, pos_out);
    // B: xws = (x @ W1[:,3:].T) * s1      (BM=64 -> 512 blocks)
    gemm_bn_kernel<64, 128, 0><<<dim3(512, 1), 256, 0, stream>>>(
        x, W1, 131, 3, g1, b1, m1, v1, nullptr, xws, 128);
    // C: gather + max-pool -> f_inc (all), f_exc (flagged)
    group_max_kernel<<<8192, 256, 0, stream>>>(
        pos, idx_inc, idx_exc, flags, xws, W1, g1, b1, m1, v1, f_inc, f_exc);
    // D1: h1 = relu(bn2(f_inc @ W2.T))    (BM=128 -> 256x4 blocks)
    gemm_bn_kernel<128, 128, 1><<<dim3(256, 4), 256, 0, stream>>>(
        f_inc, W2, 128, 0, g2, b2, m2, v2, nullptr, h1, 512);
    // D2: y_out = relu(x + bn3(h1 @ W3.T)) (BM=64 -> 512 blocks)
    gemm_bn_kernel<64, 512, 2><<<dim3(512, 1), 256, 0, stream>>>(
        h1, W3, 512, 0, g3, b3, m3, v3, x, y_out, 128);
    // E: flagged points -> output-space midpoint with exc-list MLP
    fixup_kernel<<<8192, 256, 0, stream>>>(
        flags, f_exc, x, W2, g2, b2, m2, v2, W3, g3, b3, m3, v3, y_out);
}

// Round 19
// 281.070 us; speedup vs baseline: 1.1633x; 1.1633x over previous
//
#include <hip/hip_runtime.h>
#include <cstdint>
#include <cstddef>

#define NPTS 4096
#define KNB 32
#define EPSC 1e-5f

typedef short short8v __attribute__((ext_vector_type(8)));
typedef float f32x4 __attribute__((ext_vector_type(4)));
typedef unsigned short u16;

__device__ __forceinline__ u16 f2bf(float x) {
    unsigned u = __float_as_uint(x);
    u = (u + 0x7FFFu + ((u >> 16) & 1u)) >> 16;
    return (u16)u;
}
__device__ __forceinline__ float bf2f(u16 h) {
    return __uint_as_float((unsigned)h << 16);
}

// ---------------------------------------------------------------------------
// split: f32 -> (bf16 hi, bf16 lo) arrays (RNE both stages)
// ---------------------------------------------------------------------------
__global__ __launch_bounds__(256) void split_kernel(
    const float* __restrict__ src, u16* __restrict__ hi, u16* __restrict__ lo, int n)
{
    int i = blockIdx.x * 256 + threadIdx.x;
    if (i < n) {
        float v = src[i];
        u16 h = f2bf(v);
        hi[i] = h;
        lo[i] = f2bf(v - bf2f(h));
    }
}

// ---------------------------------------------------------------------------
// Kernel A: ball query, wave per 4 points, joint scan (r16). Pure-f32 band.
// ---------------------------------------------------------------------------
__global__ __launch_bounds__(1024) void ball_query_kernel(
    const float* __restrict__ pos, int* __restrict__ idx_inc,
    int* __restrict__ idx_exc, int* __restrict__ flags,
    float* __restrict__ pos_out)
{
    __shared__ float sx[NPTS], sy[NPTS], sz[NPTS];   // 48 KB
    const int tid  = threadIdx.x;
    const int lane = tid & 63;
    const int wv   = tid >> 6;                       // 0..15
    const int pbase = blockIdx.x * 64;               // 64 points per block
    const int b = pbase >> 12;
    const float* pb = pos + (size_t)b * NPTS * 3;

    const float T_HI = (float)(0.0225 + 3e-7);
    const float T_LO = (float)(0.0225 - 3e-7);

    for (int j = tid; j < NPTS; j += 1024) {
        sx[j] = pb[j*3+0]; sy[j] = pb[j*3+1]; sz[j] = pb[j*3+2];
    }
    if ((pbase & (NPTS - 1)) == 0) {                 // pos passthrough
        const float4* src = (const float4*)pb;
        float4* dst = (float4*)(pos_out + (size_t)b * NPTS * 3);
        for (int i = tid; i < NPTS * 3 / 4; i += 1024) dst[i] = src[i];
    }
    __syncthreads();

    const int p0 = pbase + wv * 4;                   // this wave's 4 points
    float px[4], py[4], pz[4];
    int cnt[4]   = {0, 0, 0, 0};
    int first[4] = {0, 0, 0, 0};
    unsigned long long dif[4] = {0ull, 0ull, 0ull, 0ull};
    int* op[4];
#pragma unroll
    for (int q = 0; q < 4; ++q) {
        const int ml = (p0 + q) & (NPTS - 1);
        px[q] = sx[ml]; py[q] = sy[ml]; pz[q] = sz[ml];
        op[q] = idx_inc + (size_t)(p0 + q) * KNB;
    }

    for (int it = 0; it < NPTS / 64; ++it) {
        const int j = it * 64 + lane;
        const float cx = sx[j], cy = sy[j], cz = sz[j];
        int ndone = 0;
#pragma unroll
        for (int q = 0; q < 4; ++q) {
            if (cnt[q] < KNB) {                      // wave-uniform branch
                const float dx = px[q] - cx, dy = py[q] - cy, dz = pz[q] - cz;
                const float d2 = fmaf(dx, dx, fmaf(dy, dy, dz * dz));
                const unsigned long long mi = __ballot(d2 < T_HI);
                const unsigned long long me = __ballot(d2 < T_LO);
                dif[q] |= (mi ^ me);
                if (cnt[q] == 0 && mi) first[q] = it * 64 + __ffsll(mi) - 1;
                if (d2 < T_HI) {
                    const int r = cnt[q] + (int)__builtin_amdgcn_mbcnt_hi(
                        (unsigned)(mi >> 32),
                        __builtin_amdgcn_mbcnt_lo((unsigned)mi, 0u));
                    if (r < KNB) op[q][r] = j;
                }
                cnt[q] += __popcll(mi);
            } else {
                ndone++;
            }
        }
        if (ndone == 4) break;
    }

#pragma unroll
    for (int q = 0; q < 4; ++q) {
        const int si = cnt[q] < KNB ? cnt[q] : KNB;
        if (lane >= si && lane < KNB) op[q][lane] = first[q];   // pad w/ first hit
        const int flg = (dif[q] != 0ull) ? 1 : 0;
        if (flg) {                                   // rare, wave-uniform
            int cnt_e = 0, first_e = 0;
            int* oe = idx_exc + (size_t)(p0 + q) * KNB;
            const float qx = px[q], qy = py[q], qz = pz[q];
            for (int it = 0; it < NPTS / 64; ++it) {
                const int j = it * 64 + lane;
                const float dx = qx - sx[j], dy = qy - sy[j], dz = qz - sz[j];
                const float d2 = fmaf(dx, dx, fmaf(dy, dy, dz * dz));
                const unsigned long long me = __ballot(d2 < T_LO);
                if (cnt_e == 0 && me) first_e = it * 64 + __ffsll(me) - 1;
                if (d2 < T_LO) {
                    const int r = cnt_e + (int)__builtin_amdgcn_mbcnt_hi(
                        (unsigned)(me >> 32),
                        __builtin_amdgcn_mbcnt_lo((unsigned)me, 0u));
                    if (r < KNB) oe[r] = j;
                }
                cnt_e += __popcll(me);
                if (cnt_e >= KNB) break;
            }
            const int se = cnt_e < KNB ? cnt_e : KNB;
            if (lane >= se && lane < KNB) oe[lane] = first_e;
        }
        if (lane == 0) flags[p0 + q] = flg;
    }
}

// ---------------------------------------------------------------------------
// f32 tiled GEMM (kept for B only): C = (A @ W[:,woff:]^T) * s
// ---------------------------------------------------------------------------
template<int BM, int KTOT, int EPI>
__global__ __launch_bounds__(256) void gemm_bn_kernel(
    const float* __restrict__ A, const float* __restrict__ W,
    int wstride, int woff,
    const float* __restrict__ gg, const float* __restrict__ bb,
    const float* __restrict__ mm, const float* __restrict__ vv,
    const float* __restrict__ X,
    float* __restrict__ C, int cstride)
{
    constexpr int MR = BM / 16;
    __shared__ float At[32][BM + 1];
    __shared__ float Wt[32][129];
    const int tid  = threadIdx.x;
    const int lane = tid & 63;
    const int wv   = tid >> 6;
    const int tr = ((wv >> 1) << 3) | (lane >> 3);
    const int tc = ((wv & 1) << 3) | (lane & 7);
    const int rowbase = blockIdx.x * BM;
    const int colbase = blockIdx.y * 128;
    const int k4   = (tid & 7) * 4;
    const int lrow = tid >> 3;

    float acc[MR][8];
#pragma unroll
    for (int i = 0; i < MR; ++i)
#pragma unroll
        for (int j = 0; j < 8; ++j) acc[i][j] = 0.f;

    for (int kc = 0; kc < KTOT / 32; ++kc) {
        __syncthreads();
#pragma unroll
        for (int p = 0; p < BM / 32; ++p) {
            const int r = lrow + p * 32;
            const float4 v = *(const float4*)&A[(size_t)(rowbase + r) * KTOT + kc * 32 + k4];
            At[k4+0][r] = v.x; At[k4+1][r] = v.y;
            At[k4+2][r] = v.z; At[k4+3][r] = v.w;
        }
#pragma unroll
        for (int p = 0; p < 4; ++p) {
            const int c = lrow + p * 32;
            const float* wp = &W[(size_t)(colbase + c) * wstride + woff + kc * 32 + k4];
            Wt[k4+0][c] = wp[0]; Wt[k4+1][c] = wp[1];
            Wt[k4+2][c] = wp[2]; Wt[k4+3][c] = wp[3];
        }
        __syncthreads();
#pragma unroll 4
        for (int kk = 0; kk < 32; ++kk) {
            float a[MR], w[8];
            if constexpr (MR == 8) {
                *(float4*)&a[0] = *(const float4*)&At[kk][tr*8];
                *(float4*)&a[4] = *(const float4*)&At[kk][tr*8+4];
            } else {
                *(float4*)&a[0] = *(const float4*)&At[kk][tr*4];
            }
            *(float4*)&w[0] = *(const float4*)&Wt[kk][tc*8];
            *(float4*)&w[4] = *(const float4*)&Wt[kk][tc*8+4];
#pragma unroll
            for (int i = 0; i < MR; ++i)
#pragma unroll
                for (int j = 0; j < 8; ++j)
                    acc[i][j] = fmaf(a[i], w[j], acc[i][j]);
        }
    }

    float s[8], t[8];
#pragma unroll
    for (int j = 0; j < 8; ++j) {
        const int col = colbase + tc * 8 + j;
        const float sc = gg[col] / sqrtf(vv[col] + EPSC);
        s[j] = sc;
        t[j] = (EPI == 0) ? 0.f : (bb[col] - mm[col] * sc);
    }
#pragma unroll
    for (int i = 0; i < MR; ++i) {
        const int r = rowbase + tr * MR + i;
        float o[8];
#pragma unroll
        for (int j = 0; j < 8; ++j) {
            float vl = acc[i][j] * s[j];
            if (EPI != 0) vl += t[j];
            if (EPI == 2) vl += X[(size_t)r * 128 + colbase + tc * 8 + j];
            if (EPI >= 1) vl = fmaxf(vl, 0.f);
            o[j] = vl;
        }
        float* cp = &C[(size_t)r * cstride + colbase + tc * 8];
        *(float4*)&cp[0] = *(const float4*)&o[0];
        *(float4*)&cp[4] = *(const float4*)&o[4];
    }
}

// ---------------------------------------------------------------------------
// MFMA split-bf16 GEMM: C[M,N] = epi( sum_k (Ah+Al)[m,k] * (Wh+Wl)[n,k] )
// 128x128 tile/block, 4 waves in 2x2, 16x16x32 bf16 MFMA, 3-product emulation.
// EPI 1: h = relu(acc*s+t) -> split-store (Oh,Ol). EPI 2: y = relu(X + acc*s+t).
// ---------------------------------------------------------------------------
template<int KTOT, int EPI>
__global__ __launch_bounds__(256) void mfma_gemm_kernel(
    const u16* __restrict__ Ahg, const u16* __restrict__ Alg,
    const u16* __restrict__ Whg, const u16* __restrict__ Wlg,
    const float* __restrict__ gg, const float* __restrict__ bb,
    const float* __restrict__ mm, const float* __restrict__ vv,
    const float* __restrict__ X,
    u16* __restrict__ Oh, u16* __restrict__ Ol,
    float* __restrict__ Yf, int nstride)
{
    __shared__ u16 Ah[128][40];     // stride 80B: 16B-aligned b128 frag reads
    __shared__ u16 Al[128][40];
    __shared__ u16 Bh[128][40];
    __shared__ u16 Bl[128][40];
    const int tid  = threadIdx.x;
    const int lane = tid & 63;
    const int wv   = tid >> 6;
    const int rowbase = blockIdx.x * 128;
    const int colbase = blockIdx.y * 128;
    const int R0 = (wv >> 1) * 64;
    const int C0 = (wv & 1) * 64;
    const int srow = tid & 127;
    const int skh  = (tid >> 7) * 16;
    const int fr = lane & 15;
    const int fq = lane >> 4;

    f32x4 acc[4][4];
#pragma unroll
    for (int i = 0; i < 4; ++i)
#pragma unroll
        for (int j = 0; j < 4; ++j)
            acc[i][j] = (f32x4){0.f, 0.f, 0.f, 0.f};

    for (int kc = 0; kc < KTOT / 32; ++kc) {
        __syncthreads();
        const size_t ga = (size_t)(rowbase + srow) * KTOT + kc * 32 + skh;
        const size_t gw = (size_t)(colbase + srow) * KTOT + kc * 32 + skh;
        *(short8v*)&Ah[srow][skh]     = *(const short8v*)&Ahg[ga];
        *(short8v*)&Ah[srow][skh + 8] = *(const short8v*)&Ahg[ga + 8];
        *(short8v*)&Al[srow][skh]     = *(const short8v*)&Alg[ga];
        *(short8v*)&Al[srow][skh + 8] = *(const short8v*)&Alg[ga + 8];
        *(short8v*)&Bh[srow][skh]     = *(const short8v*)&Whg[gw];
        *(short8v*)&Bh[srow][skh + 8] = *(const short8v*)&Whg[gw + 8];
        *(short8v*)&Bl[srow][skh]     = *(const short8v*)&Wlg[gw];
        *(short8v*)&Bl[srow][skh + 8] = *(const short8v*)&Wlg[gw + 8];
        __syncthreads();

        short8v ahf[4], alf[4];
#pragma unroll
        for (int fi = 0; fi < 4; ++fi) {
            ahf[fi] = *(const short8v*)&Ah[R0 + fi * 16 + fr][fq * 8];
            alf[fi] = *(const short8v*)&Al[R0 + fi * 16 + fr][fq * 8];
        }
#pragma unroll
        for (int fj = 0; fj < 4; ++fj) {
            const short8v bh = *(const short8v*)&Bh[C0 + fj * 16 + fr][fq * 8];
            const short8v bl = *(const short8v*)&Bl[C0 + fj * 16 + fr][fq * 8];
#pragma unroll
            for (int fi = 0; fi < 4; ++fi) {
                acc[fi][fj] = __builtin_amdgcn_mfma_f32_16x16x32_bf16(ahf[fi], bh, acc[fi][fj], 0, 0, 0);
                acc[fi][fj] = __builtin_amdgcn_mfma_f32_16x16x32_bf16(ahf[fi], bl, acc[fi][fj], 0, 0, 0);
                acc[fi][fj] = __builtin_amdgcn_mfma_f32_16x16x32_bf16(alf[fi], bh, acc[fi][fj], 0, 0, 0);
            }
        }
    }

    // epilogue: D mapping row=(lane>>4)*4+reg, col=lane&15  [m89 verified]
#pragma unroll
    for (int fj = 0; fj < 4; ++fj) {
        const int col = colbase + C0 + fj * 16 + fr;
        const float sc = gg[col] / sqrtf(vv[col] + EPSC);
        const float tt = bb[col] - mm[col] * sc;
#pragma unroll
        for (int fi = 0; fi < 4; ++fi) {
#pragma unroll
            for (int r = 0; r < 4; ++r) {
                const int row = rowbase + R0 + fi * 16 + fq * 4 + r;
                float v = acc[fi][fj][r] * sc + tt;
                if (EPI == 2) v += X[(size_t)row * 128 + col];
                v = fmaxf(v, 0.f);
                if (EPI == 1) {
                    const u16 h = f2bf(v);
                    Oh[(size_t)row * nstride + col] = h;
                    Ol[(size_t)row * nstride + col] = f2bf(v - bf2f(h));
                } else {
                    Yf[(size_t)row * 128 + col] = v;
                }
            }
        }
    }
}

// ---------------------------------------------------------------------------
// Kernel C: gather + rel contribution + max-pool (r14 structure). f written
// as bf16 hi/lo pair (fh, fl) for the MFMA consumer; f_exc stays f32.
// ---------------------------------------------------------------------------
__global__ __launch_bounds__(256) void group_max_kernel(
    const float* __restrict__ pos, const int* __restrict__ idx_inc,
    const int* __restrict__ idx_exc, const int* __restrict__ flags,
    const float* __restrict__ xws,
    const float* __restrict__ W1, const float* __restrict__ g1,
    const float* __restrict__ b1, const float* __restrict__ m1,
    const float* __restrict__ v1,
    u16* __restrict__ fh, u16* __restrict__ fl, float* __restrict__ f_exc)
{
    __shared__ float4 relbuf[2][4][KNB];             // 4 KB
    const int tid  = threadIdx.x;
    const int lane = tid & 63;
    const int wv   = tid >> 6;
    const int p = blockIdx.x * 4 + wv;
    const int b = p >> 12;
    const int mloc = p & (NPTS - 1);
    const float* pb = pos + (size_t)b * NPTS * 3;
    const char* xws_b = (const char*)(xws + (size_t)b * NPTS * 128);
    const int o0 = lane * 2;
    const int lane8 = lane * 8;

    const float w00 = W1[(size_t)o0*131+0], w01 = W1[(size_t)o0*131+1], w02 = W1[(size_t)o0*131+2];
    const float w10 = W1[(size_t)(o0+1)*131+0], w11 = W1[(size_t)(o0+1)*131+1], w12 = W1[(size_t)(o0+1)*131+2];
    const float s0 = g1[o0]   / sqrtf(v1[o0]   + EPSC);
    const float s1 = g1[o0+1] / sqrtf(v1[o0+1] + EPSC);
    const float t0 = b1[o0]   - m1[o0]   * s0;
    const float t1 = b1[o0+1] - m1[o0+1] * s1;
    const float q00 = w00*s0, q01 = w01*s0, q02 = w02*s0;
    const float q10 = w10*s1, q11 = w11*s1, q12 = w12*s1;

    const float pmx = pb[mloc*3+0], pmy = pb[mloc*3+1], pmz = pb[mloc*3+2];
    const int flg = flags[p];

    {   // preload inc table
        const int j = idx_inc[(size_t)p * KNB + (lane & 31)];
        const float* pj = &pb[j*3];
        const float rx = (pj[0] - pmx) / 0.15f;
        const float ry = (pj[1] - pmy) / 0.15f;
        const float rz = (pj[2] - pmz) / 0.15f;
        if (lane < KNB)
            relbuf[0][wv][lane] = make_float4(rx, ry, rz, __int_as_float(j << 9));
    }
    if (flg) {  // preload exc table (rare; no barrier inside)
        const int j = idx_exc[(size_t)p * KNB + (lane & 31)];
        const float* pj = &pb[j*3];
        const float rx = (pj[0] - pmx) / 0.15f;
        const float ry = (pj[1] - pmy) / 0.15f;
        const float rz = (pj[2] - pmz) / 0.15f;
        if (lane < KNB)
            relbuf[1][wv][lane] = make_float4(rx, ry, rz, __int_as_float(j << 9));
    }
    __syncthreads();

    {
        const float4* rt = relbuf[0][wv];
        float acc0 = 0.f, acc1 = 0.f;
#pragma unroll 8
        for (int k = 0; k < KNB; ++k) {
            const float4 rv = rt[k];
            const int ofs = __float_as_int(rv.w);
            const float2 xw = *(const float2*)(xws_b + ofs + lane8);
            const float v0 = fmaf(rv.x, q00, fmaf(rv.y, q01, fmaf(rv.z, q02, t0 + xw.x)));
            const float v1v = fmaf(rv.x, q10, fmaf(rv.y, q11, fmaf(rv.z, q12, t1 + xw.y)));
            acc0 = fmaxf(acc0, v0);
            acc1 = fmaxf(acc1, v1v);
        }
        const u16 h0 = f2bf(acc0); const u16 l0 = f2bf(acc0 - bf2f(h0));
        const u16 h1 = f2bf(acc1); const u16 l1 = f2bf(acc1 - bf2f(h1));
        *(unsigned*)&fh[(size_t)p * 128 + o0] = (unsigned)h0 | ((unsigned)h1 << 16);
        *(unsigned*)&fl[(size_t)p * 128 + o0] = (unsigned)l0 | ((unsigned)l1 << 16);
    }
    if (flg) {
        const float4* rt = relbuf[1][wv];
        float e0 = 0.f, e1 = 0.f;
#pragma unroll 8
        for (int k = 0; k < KNB; ++k) {
            const float4 rv = rt[k];
            const int ofs = __float_as_int(rv.w);
            const float2 xw = *(const float2*)(xws_b + ofs + lane8);
            const float v0 = fmaf(rv.x, q00, fmaf(rv.y, q01, fmaf(rv.z, q02, t0 + xw.x)));
            const float v1v = fmaf(rv.x, q10, fmaf(rv.y, q11, fmaf(rv.z, q12, t1 + xw.y)));
            e0 = fmaxf(e0, v0);
            e1 = fmaxf(e1, v1v);
        }
        float2 ev; ev.x = e0; ev.y = e1;
        *(float2*)&f_exc[(size_t)p * 128 + o0] = ev;
    }
}

// ---------------------------------------------------------------------------
// Kernel E: per-flagged-point f32 MLP on f_exc; blend OUTPUT-space midpoint.
// ---------------------------------------------------------------------------
__global__ __launch_bounds__(256) void fixup_kernel(
    const int* __restrict__ flags, const float* __restrict__ f_exc,
    const float* __restrict__ x,
    const float* __restrict__ W2, const float* __restrict__ g2,
    const float* __restrict__ b2, const float* __restrict__ m2,
    const float* __restrict__ v2,
    const float* __restrict__ W3, const float* __restrict__ g3,
    const float* __restrict__ b3, const float* __restrict__ m3,
    const float* __restrict__ v3,
    float* __restrict__ y_out)
{
    const int lane = threadIdx.x & 63;
    const int wv   = threadIdx.x >> 6;
    const int p = blockIdx.x * 4 + wv;
    if (flags[p] == 0) return;

    const float2 fv = *(const float2*)&f_exc[(size_t)p * 128 + 2 * lane];

    float acc[8];
#pragma unroll
    for (int u = 0; u < 8; ++u) acc[u] = 0.f;
    for (int cc = 0; cc < 64; ++cc) {
        float fx = __shfl(fv.x, cc);
        float fy = __shfl(fv.y, cc);
#pragma unroll
        for (int u = 0; u < 8; ++u) {
            const float* wr = &W2[(size_t)(64 * u + lane) * 128 + 2 * cc];
            acc[u] += fx * wr[0] + fy * wr[1];
        }
    }
    float hreg[8];
#pragma unroll
    for (int u = 0; u < 8; ++u) {
        int o = 64 * u + lane;
        float s = g2[o] / sqrtf(v2[o] + EPSC);
        float t = b2[o] - m2[o] * s;
        hreg[u] = fmaxf(acc[u] * s + t, 0.f);
    }

    const int o0 = 2 * lane, o1 = 2 * lane + 1;
    float a0 = 0.f, a1 = 0.f;
#pragma unroll
    for (int u = 0; u < 8; ++u) {
        float hu = hreg[u];
        for (int cc = 0; cc < 64; ++cc) {
            float hc = __shfl(hu, cc);
            int c = 64 * u + cc;
            a0 += hc * W3[(size_t)o0 * 512 + c];
            a1 += hc * W3[(size_t)o1 * 512 + c];
        }
    }
    float s0 = g3[o0] / sqrtf(v3[o0] + EPSC), t0 = b3[o0] - m3[o0] * s0;
    float s1 = g3[o1] / sqrtf(v3[o1] + EPSC), t1 = b3[o1] - m3[o1] * s1;
    float e0 = fmaxf(a0 * s0 + t0 + x[(size_t)p * 128 + o0], 0.f);
    float e1 = fmaxf(a1 * s1 + t1 + x[(size_t)p * 128 + o1], 0.f);

    float2 cur = *(float2*)&y_out[(size_t)p * 128 + o0];
    float2 nv; nv.x = 0.5f * (cur.x + e0); nv.y = 0.5f * (cur.y + e1);
    *(float2*)&y_out[(size_t)p * 128 + o0] = nv;
}

// ---------------------------------------------------------------------------
extern "C" void kernel_launch(void* const* d_in, const int* in_sizes, int n_in,
                              void* d_out, int out_size, void* d_ws, size_t ws_size,
                              hipStream_t stream)
{
    const float* pos = (const float*)d_in[0];
    const float* x   = (const float*)d_in[1];
    const float* W1  = (const float*)d_in[2];
    const float* g1  = (const float*)d_in[3];
    const float* b1  = (const float*)d_in[4];
    const float* m1  = (const float*)d_in[5];
    const float* v1  = (const float*)d_in[6];
    const float* W2  = (const float*)d_in[7];
    const float* g2  = (const float*)d_in[8];
    const float* b2  = (const float*)d_in[9];
    const float* m2  = (const float*)d_in[10];
    const float* v2  = (const float*)d_in[11];
    const float* W3  = (const float*)d_in[12];
    const float* g3  = (const float*)d_in[13];
    const float* b3  = (const float*)d_in[14];
    const float* m3  = (const float*)d_in[15];
    const float* v3  = (const float*)d_in[16];

    float* out = (float*)d_out;
    float* pos_out = out;                     // 8*4096*3 floats
    float* y_out   = out + 98304;             // 8*4096*128 floats

    char* ws = (char*)d_ws;
    int*   idx_inc = (int*)ws;                                    // 4 MB @ 0
    int*   idx_exc = (int*)(ws + ((size_t)4  << 20));             // 4 MB @ 4M
    int*   flags   = (int*)(ws + ((size_t)8  << 20));             // 128 KB @ 8M
    u16*   W2h     = (u16*)(ws + ((size_t)8  << 20) + (128u<<10));// 128 KB
    u16*   W2l     = (u16*)(ws + ((size_t)8  << 20) + (256u<<10));// 128 KB
    u16*   W3h     = (u16*)(ws + ((size_t)8  << 20) + (384u<<10));// 128 KB
    u16*   W3l     = (u16*)(ws + ((size_t)8  << 20) + (512u<<10));// 128 KB
    float* xws     = (float*)(ws + ((size_t)9  << 20));           // 16 MB @ 9M
    u16*   fh      = (u16*)(ws + ((size_t)25 << 20));             // 8 MB @ 25M
    u16*   fl      = (u16*)(ws + ((size_t)33 << 20));             // 8 MB @ 33M
    float* f_exc   = (float*)(ws + ((size_t)41 << 20));           // 16 MB @ 41M
    u16*   hh      = (u16*)(ws + ((size_t)57 << 20));             // 32 MB @ 57M
    u16*   hl      = (u16*)(ws + ((size_t)89 << 20));             // 32 MB @ 89M
    (void)ws_size; (void)in_sizes; (void)n_in; (void)out_size;

    // P: split W2/W3 into bf16 hi/lo
    split_kernel<<<256, 256, 0, stream>>>(W2, W2h, W2l, 512 * 128);
    split_kernel<<<256, 256, 0, stream>>>(W3, W3h, W3l, 128 * 512);
    // A: ball query (joint 4-point scan) + pos passthrough
    ball_query_kernel<<<512, 1024, 0, stream>>>(pos, idx_inc, idx_exc, flags, pos_out);
    // B: xws = (x @ W1[:,3:].T) * s1  (f32)
    gemm_bn_kernel<64, 128, 0><<<dim3(512, 1), 256, 0, stream>>>(
        x, W1, 131, 3, g1, b1, m1, v1, nullptr, xws, 128);
    // C: gather + max-pool -> (fh,fl) all, f_exc flagged
    group_max_kernel<<<8192, 256, 0, stream>>>(
        pos, idx_inc, idx_exc, flags, xws, W1, g1, b1, m1, v1, fh, fl, f_exc);
    // D1: (hh,hl) = split(relu(bn2(f @ W2^T)))  [MFMA split-bf16]
    mfma_gemm_kernel<128, 1><<<dim3(256, 4), 256, 0, stream>>>(
        fh, fl, W2h, W2l, g2, b2, m2, v2, nullptr, hh, hl, nullptr, 512);
    // D2: y = relu(x + bn3(h @ W3^T))           [MFMA split-bf16]
    mfma_gemm_kernel<512, 2><<<dim3(256, 1), 256, 0, stream>>>(
        hh, hl, W3h, W3l, g3, b3, m3, v3, x, nullptr, nullptr, y_out, 128);
    // E: flagged points -> output-space midpoint with exc-list f32 MLP
    fixup_kernel<<<8192, 256, 0, stream>>>(
        flags, f_exc, x, W2, g2, b2, m2, v2, W3, g3, b3, m3, v3, y_out);
}